// Round 11
// baseline (118.003 us; speedup 1.0000x reference)
//
#include <hip/hip_runtime.h>

// LearnableDemosaick: B=16,H=512,W=512,K=8,f=5, fp32.
// out = is_green ? mosaick : softmax_k(sel_conv) . green_conv
// is_green = (y%2)==(x%2). Edge-clamped 5x5 cross-correlation.
//
// Round-11: MEASUREMENT ROUND. R10 byte-identical, but the main kernel is
// launched 3x (idempotent: const inputs -> deterministic outputs). The bench
// delta vs R10 gives the main kernel's true duration with the harness floor
// cancelling: T_main = (bench_R11 - 85.2) / 2. Decides between
// "kernel ~26us (hidden pathology)" and "kernel ~8us (floor bigger than
// modeled)" -- three rounds of model/measurement mismatch hinge on this.

typedef float f32x16 __attribute__((ext_vector_type(16)));
typedef short s16x8  __attribute__((ext_vector_type(8)));

#define HH 512
#define WW 512
#define TW 64
#define TH 16
#define RS 80     // LDS row stride (bf16 elems) = 160 B
#define NROW 20   // TH + 4
#define NEL 72    // staged elems per row (9 chunks of 8)

__device__ __forceinline__ unsigned short bf16rne(float x) {
    unsigned u = __float_as_uint(x);
    u += 0x7fffu + ((u >> 16) & 1u);
    return (unsigned short)(u >> 16);
}
__device__ __forceinline__ int pk2(float hi, float lo) {
    return (int)((((unsigned)bf16rne(hi)) << 16) | (unsigned)bf16rne(lo));
}
__device__ __forceinline__ float hi16(int v) { return __uint_as_float(((unsigned)v) & 0xffff0000u); }
__device__ __forceinline__ float lo16(int v) { return __uint_as_float(((unsigned)v) << 16); }

// ---- setup: build the 6 per-lane A fragments once into ws ----
__global__ void build_frags_kernel(const float* __restrict__ sf,
                                   const float* __restrict__ gf,
                                   short* __restrict__ ws)
{
    const int lane = threadIdx.x;     // 0..63
    const int mm   = lane & 31;
    const int h    = (lane >> 5) & 1;
    const int c    = mm >> 1;
    const bool tg  = mm & 1;
    const bool chok = mm < 16;
    const float* fb = tg ? gf : sf;

    s16x8 A[6];
#pragma unroll
    for (int f = 0; f < 6; ++f)
#pragma unroll
        for (int j = 0; j < 8; ++j) A[f][j] = 0;

#pragma unroll
    for (int j = 0; j < 8; ++j) {
        const int dx0 = j - 1;
        if (dx0 >= 0 && dx0 < 5 && chok) {
            A[0][j] = (short)bf16rne(fb[((h)     * 5 + dx0) * 8 + c]);
            A[1][j] = (short)bf16rne(fb[((2 + h) * 5 + dx0) * 8 + c]);
            if (h == 0)
                A[2][j] = (short)bf16rne(fb[(4 * 5 + dx0) * 8 + c]);
        }
        const int dx1 = j;
        if (dx1 < 5 && chok) {
            if (h == 1)
                A[3][j] = (short)bf16rne(fb[(0 * 5 + dx1) * 8 + c]);
            A[4][j] = (short)bf16rne(fb[((1 + h) * 5 + dx1) * 8 + c]);
            A[5][j] = (short)bf16rne(fb[((3 + h) * 5 + dx1) * 8 + c]);
        }
    }
    s16x8* dst = (s16x8*)(ws + lane * 48);
#pragma unroll
    for (int f = 0; f < 6; ++f) dst[f] = A[f];
}

__global__ __launch_bounds__(256) void demosaick_kernel(
    const float* __restrict__ mos,   // [B,1,H,W]
    const short* __restrict__ frg,   // per-lane A fragments (from ws)
    float* __restrict__ out)         // [B,1,H,W]
{
    __shared__ alignas(16) unsigned short tileS[NROW * RS];

    const int tid   = threadIdx.x;
    const int bx    = blockIdx.x;
    const int by    = blockIdx.y;
    const int bimg  = blockIdx.z;
    const int tileX = bx * TW;    // even
    const int tileY = by * TH;    // even
    const float* img = mos + (size_t)bimg * HH * WW;

    const bool interior = (bx >= 1) && (bx <= 6) && (by >= 1) && (by <= 30);
    if (interior) {
        if (tid < 180) {                       // 20 rows x 9 chunks of 8 elems
            int r = tid / 9, s = tid - 9 * r;
            const float2* src = (const float2*)(img + (size_t)(tileY - 2 + r) * WW
                                                + (tileX - 2 + 8 * s));
            float2 v0 = src[0], v1 = src[1], v2 = src[2], v3 = src[3];
            int4 d;
            d.x = pk2(v0.y, v0.x);
            d.y = pk2(v1.y, v1.x);
            d.z = pk2(v2.y, v2.x);
            d.w = pk2(v3.y, v3.x);
            *(int4*)&tileS[r * RS + 8 * s] = d;
        }
    } else {
        for (int i = tid; i < NROW * NEL; i += 256) {
            int r = i / NEL, e = i - NEL * r;
            int gy = min(max(tileY - 2 + r, 0), HH - 1);
            int gx = min(max(tileX - 2 + e, 0), WW - 1);
            tileS[r * RS + e] = bf16rne(img[(size_t)gy * WW + gx]);
        }
    }

    const int lane = tid & 63;
    const int w    = tid >> 6;
    const int n    = lane & 31;
    const int h    = lane >> 5;

    const s16x8* wsf = (const s16x8*)(frg + lane * 48);
    const s16x8 Aa0 = wsf[0], Ab0 = wsf[1], Ac0 = wsf[2];
    const s16x8 Aa1 = wsf[3], Ab1 = wsf[4], Ac1 = wsf[5];

    __syncthreads();

    const int* tb = (const int*)tileS;     // 40 ints per row
    float* outp = out + (size_t)bimg * HH * WW;

#pragma unroll
    for (int pp = 0; pp < 2; ++pp) {
        const int Rl = 4 * w + 2 * pp;
        const int y  = tileY + Rl;
        const int ia = (Rl + h) * 40 + n;

        union { int4 v; s16x8 s; } Ba, Bb, Bc;
        Ba.v.x = tb[ia];       Ba.v.y = tb[ia + 1];
        Ba.v.z = tb[ia + 2];   Ba.v.w = tb[ia + 3];
        Bb.v.x = tb[ia + 80];  Bb.v.y = tb[ia + 81];
        Bb.v.z = tb[ia + 82];  Bb.v.w = tb[ia + 83];
        Bc.v.x = tb[ia + 160]; Bc.v.y = tb[ia + 161];
        Bc.v.z = tb[ia + 162]; Bc.v.w = tb[ia + 163];

        f32x16 acc = (f32x16)(0.f);
        acc = __builtin_amdgcn_mfma_f32_32x32x16_bf16(Aa0, Ba.s, acc, 0, 0, 0);
        acc = __builtin_amdgcn_mfma_f32_32x32x16_bf16(Ab0, Bb.s, acc, 0, 0, 0);
        acc = __builtin_amdgcn_mfma_f32_32x32x16_bf16(Ac0, Bc.s, acc, 0, 0, 0);
        {
            float den = 0.f, num = 0.f;
#pragma unroll
            for (int j = 0; j < 4; ++j) {
                float e = __expf(acc[2 * j]);
                den += e;
                num = fmaf(e, acc[2 * j + 1], num);
            }
            int nd  = pk2(num, den);
            int nd2 = __shfl_xor(nd, 32);
            num += hi16(nd2);
            den += lo16(nd2);
            const float interp = num * __builtin_amdgcn_rcpf(den);
            if (h == 0) {
                const int x0 = tileX + 2 * n;
                const float green = img[(size_t)y * WW + x0];
                float2 st; st.x = green; st.y = interp;
                *(float2*)(outp + (size_t)y * WW + x0) = st;
            }
        }

        f32x16 acc2 = (f32x16)(0.f);
        acc2 = __builtin_amdgcn_mfma_f32_32x32x16_bf16(Aa1, Ba.s, acc2, 0, 0, 0);
        acc2 = __builtin_amdgcn_mfma_f32_32x32x16_bf16(Ab1, Bb.s, acc2, 0, 0, 0);
        acc2 = __builtin_amdgcn_mfma_f32_32x32x16_bf16(Ac1, Bc.s, acc2, 0, 0, 0);
        {
            float den = 0.f, num = 0.f;
#pragma unroll
            for (int j = 0; j < 4; ++j) {
                float e = __expf(acc2[2 * j]);
                den += e;
                num = fmaf(e, acc2[2 * j + 1], num);
            }
            int nd  = pk2(num, den);
            int nd2 = __shfl_xor(nd, 32);
            num += hi16(nd2);
            den += lo16(nd2);
            const float interp = num * __builtin_amdgcn_rcpf(den);
            if (h == 0) {
                const int x0 = tileX + 2 * n;
                const float green = img[(size_t)(y + 1) * WW + x0 + 1];
                float2 st; st.x = interp; st.y = green;
                *(float2*)(outp + (size_t)(y + 1) * WW + x0) = st;
            }
        }
    }
}

extern "C" void kernel_launch(void* const* d_in, const int* in_sizes, int n_in,
                              void* d_out, int out_size, void* d_ws, size_t ws_size,
                              hipStream_t stream) {
    const float* mos = (const float*)d_in[0];
    const float* sf  = (const float*)d_in[1];
    const float* gf  = (const float*)d_in[2];
    float* out = (float*)d_out;
    short* ws  = (short*)d_ws;

    const int B = in_sizes[0] / (HH * WW);     // 16

    build_frags_kernel<<<1, 64, 0, stream>>>(sf, gf, ws);

    dim3 grid(WW / TW, HH / TH, B);            // (8, 32, 16) = 4096 blocks
    dim3 block(256);
    // 3x launch: idempotent; bench delta vs R10 = 2 x T_main (floor cancels)
    demosaick_kernel<<<grid, block, 0, stream>>>(mos, (const short*)ws, out);
    demosaick_kernel<<<grid, block, 0, stream>>>(mos, (const short*)ws, out);
    demosaick_kernel<<<grid, block, 0, stream>>>(mos, (const short*)ws, out);
}

// Round 12
// 86.769 us; speedup vs baseline: 1.3600x; 1.3600x over previous
//
#include <hip/hip_runtime.h>

// LearnableDemosaick: B=16,H=512,W=512,K=8,f=5, fp32.
// out = is_green ? mosaick : softmax_k(sel_conv) . green_conv
// is_green = (y%2)==(x%2). Edge-clamped 5x5 cross-correlation.
//
// Round-12: R11 measured T_main = 16.4us (3x-launch delta). Static VALU is
// only ~2us => latency-bound at ~4 waves/SIMD on the per-wave critical path
// (stage VMEM ~900cyc + barrier + ds + 3-deep MFMA chain + serial epilogue
// with 120cyc shfl). Shorten the path, widen ILP:
//  * B-frag reuse across row pairs: 4 distinct frags, 16 ds_read (was 24)
//  * all B loads up front, 12 MFMAs as 4 independent chains
//  * epilogue split across wave halves: h=0 rows 4w,4w+1; h=1 rows 4w+2,
//    4w+3 -> 2 packed xor32 shfls, 2 stores/lane, no exec-masked idle half

typedef float f32x16 __attribute__((ext_vector_type(16)));
typedef short s16x8  __attribute__((ext_vector_type(8)));

#define HH 512
#define WW 512
#define TW 64
#define TH 16
#define RS 80     // LDS row stride (bf16 elems) = 160 B
#define NROW 20   // TH + 4
#define NEL 72    // staged elems per row (9 chunks of 8)

__device__ __forceinline__ unsigned short bf16rne(float x) {
    unsigned u = __float_as_uint(x);
    u += 0x7fffu + ((u >> 16) & 1u);
    return (unsigned short)(u >> 16);
}
__device__ __forceinline__ int pk2(float hi, float lo) {
    return (int)((((unsigned)bf16rne(hi)) << 16) | (unsigned)bf16rne(lo));
}
__device__ __forceinline__ float hi16(int v) { return __uint_as_float(((unsigned)v) & 0xffff0000u); }
__device__ __forceinline__ float lo16(int v) { return __uint_as_float(((unsigned)v) << 16); }

// ---- setup: build the 6 per-lane A fragments once into ws ----
// layout: ws_short[lane*48 + frag*8 + j], frag order {Aa0,Ab0,Ac0,Aa1,Ab1,Ac1}
__global__ void build_frags_kernel(const float* __restrict__ sf,
                                   const float* __restrict__ gf,
                                   short* __restrict__ ws)
{
    const int lane = threadIdx.x;     // 0..63
    const int mm   = lane & 31;
    const int h    = (lane >> 5) & 1;
    const int c    = mm >> 1;
    const bool tg  = mm & 1;
    const bool chok = mm < 16;
    const float* fb = tg ? gf : sf;

    s16x8 A[6];
#pragma unroll
    for (int f = 0; f < 6; ++f)
#pragma unroll
        for (int j = 0; j < 8; ++j) A[f][j] = 0;

#pragma unroll
    for (int j = 0; j < 8; ++j) {
        const int dx0 = j - 1;
        if (dx0 >= 0 && dx0 < 5 && chok) {
            A[0][j] = (short)bf16rne(fb[((h)     * 5 + dx0) * 8 + c]);
            A[1][j] = (short)bf16rne(fb[((2 + h) * 5 + dx0) * 8 + c]);
            if (h == 0)
                A[2][j] = (short)bf16rne(fb[(4 * 5 + dx0) * 8 + c]);
        }
        const int dx1 = j;
        if (dx1 < 5 && chok) {
            if (h == 1)
                A[3][j] = (short)bf16rne(fb[(0 * 5 + dx1) * 8 + c]);
            A[4][j] = (short)bf16rne(fb[((1 + h) * 5 + dx1) * 8 + c]);
            A[5][j] = (short)bf16rne(fb[((3 + h) * 5 + dx1) * 8 + c]);
        }
    }
    s16x8* dst = (s16x8*)(ws + lane * 48);
#pragma unroll
    for (int f = 0; f < 6; ++f) dst[f] = A[f];
}

__global__ __launch_bounds__(256) void demosaick_kernel(
    const float* __restrict__ mos,   // [B,1,H,W]
    const short* __restrict__ frg,   // per-lane A fragments (from ws)
    float* __restrict__ out)         // [B,1,H,W]
{
    __shared__ alignas(16) unsigned short tileS[NROW * RS];

    const int tid   = threadIdx.x;
    const int bx    = blockIdx.x;
    const int by    = blockIdx.y;
    const int bimg  = blockIdx.z;
    const int tileX = bx * TW;    // even
    const int tileY = by * TH;    // even
    const float* img = mos + (size_t)bimg * HH * WW;

    // ---- load the 6 per-lane A fragments (coalesced dwordx4) ----
    const int lane = tid & 63;
    const int w    = tid >> 6;
    const int n    = lane & 31;
    const int h    = lane >> 5;

    const s16x8* wsf = (const s16x8*)(frg + lane * 48);
    const s16x8 Aa0 = wsf[0], Ab0 = wsf[1], Ac0 = wsf[2];
    const s16x8 Aa1 = wsf[3], Ab1 = wsf[4], Ac1 = wsf[5];

    // ---- stage bf16 tile rows tileY-2..tileY+17, cols tileX-2..tileX+69 ----
    const bool interior = (bx >= 1) && (bx <= 6) && (by >= 1) && (by <= 30);
    if (interior) {
        if (tid < 180) {                       // 20 rows x 9 chunks of 8 elems
            int r = tid / 9, s = tid - 9 * r;
            const float2* src = (const float2*)(img + (size_t)(tileY - 2 + r) * WW
                                                + (tileX - 2 + 8 * s));
            float2 v0 = src[0], v1 = src[1], v2 = src[2], v3 = src[3];
            int4 d;
            d.x = pk2(v0.y, v0.x);
            d.y = pk2(v1.y, v1.x);
            d.z = pk2(v2.y, v2.x);
            d.w = pk2(v3.y, v3.x);
            *(int4*)&tileS[r * RS + 8 * s] = d;
        }
    } else {
        for (int i = tid; i < NROW * NEL; i += 256) {
            int r = i / NEL, e = i - NEL * r;
            int gy = min(max(tileY - 2 + r, 0), HH - 1);
            int gx = min(max(tileX - 2 + e, 0), WW - 1);
            tileS[r * RS + e] = bf16rne(img[(size_t)gy * WW + gx]);
        }
    }
    __syncthreads();

    const int* tb = (const int*)tileS;     // 40 ints per row

    // ---- all 4 B fragments up front (rows 4w+2r+h, r=0..3) ----
    union { int4 v; s16x8 s; } B[4];
#pragma unroll
    for (int r = 0; r < 4; ++r) {
        const int ia = (4 * w + 2 * r + h) * 40 + n;
        B[r].v.x = tb[ia];     B[r].v.y = tb[ia + 1];
        B[r].v.z = tb[ia + 2]; B[r].v.w = tb[ia + 3];
    }

    // ---- 12 MFMAs, 4 independent chains ----
    // a00: row 4w   (even, conv odd x);  a01: row 4w+1 (odd, conv even x)
    // a10: row 4w+2 (even);              a11: row 4w+3 (odd)
    f32x16 a00 = (f32x16)(0.f), a01 = (f32x16)(0.f);
    f32x16 a10 = (f32x16)(0.f), a11 = (f32x16)(0.f);
    a00 = __builtin_amdgcn_mfma_f32_32x32x16_bf16(Aa0, B[0].s, a00, 0, 0, 0);
    a01 = __builtin_amdgcn_mfma_f32_32x32x16_bf16(Aa1, B[0].s, a01, 0, 0, 0);
    a10 = __builtin_amdgcn_mfma_f32_32x32x16_bf16(Aa0, B[1].s, a10, 0, 0, 0);
    a11 = __builtin_amdgcn_mfma_f32_32x32x16_bf16(Aa1, B[1].s, a11, 0, 0, 0);
    a00 = __builtin_amdgcn_mfma_f32_32x32x16_bf16(Ab0, B[1].s, a00, 0, 0, 0);
    a01 = __builtin_amdgcn_mfma_f32_32x32x16_bf16(Ab1, B[1].s, a01, 0, 0, 0);
    a10 = __builtin_amdgcn_mfma_f32_32x32x16_bf16(Ab0, B[2].s, a10, 0, 0, 0);
    a11 = __builtin_amdgcn_mfma_f32_32x32x16_bf16(Ab1, B[2].s, a11, 0, 0, 0);
    a00 = __builtin_amdgcn_mfma_f32_32x32x16_bf16(Ac0, B[2].s, a00, 0, 0, 0);
    a01 = __builtin_amdgcn_mfma_f32_32x32x16_bf16(Ac1, B[2].s, a01, 0, 0, 0);
    a10 = __builtin_amdgcn_mfma_f32_32x32x16_bf16(Ac0, B[3].s, a10, 0, 0, 0);
    a11 = __builtin_amdgcn_mfma_f32_32x32x16_bf16(Ac1, B[3].s, a11, 0, 0, 0);

    // ---- partial softmax terms for all 4 rows (in-lane, half-wave sums) ----
    float nums[4], dens[4];
    {
        const f32x16* av[4] = { &a00, &a01, &a10, &a11 };
#pragma unroll
        for (int r = 0; r < 4; ++r) {
            float den = 0.f, num = 0.f;
            const f32x16& a = *av[r];
#pragma unroll
            for (int j = 0; j < 4; ++j) {
                float e = __expf(a[2 * j]);
                den += e;
                num = fmaf(e, a[2 * j + 1], num);
            }
            nums[r] = num; dens[r] = den;
        }
    }

    // ---- cross-half exchange: h=0 finishes rows 0,1; h=1 rows 2,3 ----
    const int nd0 = pk2(nums[0], dens[0]);
    const int nd1 = pk2(nums[1], dens[1]);
    const int nd2 = pk2(nums[2], dens[2]);
    const int nd3 = pk2(nums[3], dens[3]);

    const int send0 = h ? nd0 : nd2;       // what the partner half needs
    const int send1 = h ? nd1 : nd3;
    const int rec0  = __shfl_xor(send0, 32);
    const int rec1  = __shfl_xor(send1, 32);
    const int mine0 = h ? nd2 : nd0;       // my half's rows
    const int mine1 = h ? nd3 : nd1;

    const float numA = hi16(mine0) + hi16(rec0);
    const float denA = lo16(mine0) + lo16(rec0);
    const float numB = hi16(mine1) + hi16(rec1);
    const float denB = lo16(mine1) + lo16(rec1);
    const float interpA = numA * __builtin_amdgcn_rcpf(denA);  // even row
    const float interpB = numB * __builtin_amdgcn_rcpf(denB);  // odd row

    float* outp = out + (size_t)bimg * HH * WW;
    const int y  = tileY + 4 * w + 2 * h;      // even
    const int x0 = tileX + 2 * n;              // even

    // even row: green at even x -> (green, interp); odd row: conv at even x
    const float greenA = img[(size_t)y * WW + x0];
    const float greenB = img[(size_t)(y + 1) * WW + x0 + 1];
    float2 stA; stA.x = greenA;  stA.y = interpA;
    float2 stB; stB.x = interpB; stB.y = greenB;
    *(float2*)(outp + (size_t)y * WW + x0)       = stA;
    *(float2*)(outp + (size_t)(y + 1) * WW + x0) = stB;
}

extern "C" void kernel_launch(void* const* d_in, const int* in_sizes, int n_in,
                              void* d_out, int out_size, void* d_ws, size_t ws_size,
                              hipStream_t stream) {
    const float* mos = (const float*)d_in[0];
    const float* sf  = (const float*)d_in[1];
    const float* gf  = (const float*)d_in[2];
    float* out = (float*)d_out;
    short* ws  = (short*)d_ws;

    const int B = in_sizes[0] / (HH * WW);     // 16

    build_frags_kernel<<<1, 64, 0, stream>>>(sf, gf, ws);

    dim3 grid(WW / TW, HH / TH, B);            // (8, 32, 16) = 4096 blocks
    dim3 block(256);
    demosaick_kernel<<<grid, block, 0, stream>>>(mos, (const short*)ws, out);
}

// Round 13
// 86.037 us; speedup vs baseline: 1.3715x; 1.0085x over previous
//
#include <hip/hip_runtime.h>

// LearnableDemosaick: B=16,H=512,W=512,K=8,f=5, fp32.
// out = is_green ? mosaick : softmax_k(sel_conv) . green_conv
// is_green = (y%2)==(x%2). Edge-clamped 5x5 cross-correlation.
//
// Round-13 (base = R10, best measured 85.2):
//  * greens read from the bf16 LDS tile (kills 8 MB global gather + the
//    epilogue's long-latency load; absmax ~6e-3, threshold 0.1)
//  * TH=32: halo redundancy 25%->12.5%, 2048 blocks (half the dispatches)
//  * rolling 3-frag B window over 4 row-pairs: 24 ds_read_b32 per 8 rows
// Model: T_main 16.4us = ~6.5 HBM + ~4.5 issue + ~3 dispatch; this cuts
// all three terms.

typedef float f32x16 __attribute__((ext_vector_type(16)));
typedef short s16x8  __attribute__((ext_vector_type(8)));

#define HH 512
#define WW 512
#define TW 64
#define TH 32
#define RS 80     // LDS row stride (bf16 elems) = 160 B
#define NROW 36   // TH + 4
#define NEL 72    // staged elems per row (9 chunks of 8)

__device__ __forceinline__ unsigned short bf16rne(float x) {
    unsigned u = __float_as_uint(x);
    u += 0x7fffu + ((u >> 16) & 1u);
    return (unsigned short)(u >> 16);
}
__device__ __forceinline__ int pk2(float hi, float lo) {
    return (int)((((unsigned)bf16rne(hi)) << 16) | (unsigned)bf16rne(lo));
}
__device__ __forceinline__ float hi16(int v) { return __uint_as_float(((unsigned)v) & 0xffff0000u); }
__device__ __forceinline__ float lo16(int v) { return __uint_as_float(((unsigned)v) << 16); }
__device__ __forceinline__ float bf2f(unsigned short s) {
    return __uint_as_float(((unsigned)s) << 16);
}

// ---- setup: build the 6 per-lane A fragments once into ws ----
// layout: ws_short[lane*48 + frag*8 + j], frag order {Aa0,Ab0,Ac0,Aa1,Ab1,Ac1}
__global__ void build_frags_kernel(const float* __restrict__ sf,
                                   const float* __restrict__ gf,
                                   short* __restrict__ ws)
{
    const int lane = threadIdx.x;     // 0..63
    const int mm   = lane & 31;
    const int h    = (lane >> 5) & 1;
    const int c    = mm >> 1;
    const bool tg  = mm & 1;
    const bool chok = mm < 16;
    const float* fb = tg ? gf : sf;

    s16x8 A[6];
#pragma unroll
    for (int f = 0; f < 6; ++f)
#pragma unroll
        for (int j = 0; j < 8; ++j) A[f][j] = 0;

#pragma unroll
    for (int j = 0; j < 8; ++j) {
        const int dx0 = j - 1;
        if (dx0 >= 0 && dx0 < 5 && chok) {
            A[0][j] = (short)bf16rne(fb[((h)     * 5 + dx0) * 8 + c]);
            A[1][j] = (short)bf16rne(fb[((2 + h) * 5 + dx0) * 8 + c]);
            if (h == 0)
                A[2][j] = (short)bf16rne(fb[(4 * 5 + dx0) * 8 + c]);
        }
        const int dx1 = j;
        if (dx1 < 5 && chok) {
            if (h == 1)
                A[3][j] = (short)bf16rne(fb[(0 * 5 + dx1) * 8 + c]);
            A[4][j] = (short)bf16rne(fb[((1 + h) * 5 + dx1) * 8 + c]);
            A[5][j] = (short)bf16rne(fb[((3 + h) * 5 + dx1) * 8 + c]);
        }
    }
    s16x8* dst = (s16x8*)(ws + lane * 48);
#pragma unroll
    for (int f = 0; f < 6; ++f) dst[f] = A[f];
}

__global__ __launch_bounds__(256) void demosaick_kernel(
    const float* __restrict__ mos,   // [B,1,H,W]
    const short* __restrict__ frg,   // per-lane A fragments (from ws)
    float* __restrict__ out)         // [B,1,H,W]
{
    __shared__ alignas(16) unsigned short tileS[NROW * RS];

    const int tid   = threadIdx.x;
    const int bx    = blockIdx.x;
    const int by    = blockIdx.y;
    const int bimg  = blockIdx.z;
    const int tileX = bx * TW;    // even
    const int tileY = by * TH;    // even
    const float* img = mos + (size_t)bimg * HH * WW;

    // ---- load the 6 per-lane A fragments (coalesced dwordx4) ----
    const int lane = tid & 63;
    const int w    = tid >> 6;
    const int n    = lane & 31;
    const int h    = lane >> 5;

    const s16x8* wsf = (const s16x8*)(frg + lane * 48);
    const s16x8 Aa0 = wsf[0], Ab0 = wsf[1], Ac0 = wsf[2];
    const s16x8 Aa1 = wsf[3], Ab1 = wsf[4], Ac1 = wsf[5];

    // ---- stage bf16 tile rows tileY-2..tileY+33, cols tileX-2..tileX+69 ----
    const bool interior = (bx >= 1) && (bx <= 6) && (by >= 1) && (by <= 14);
    if (interior) {
        for (int i = tid; i < NROW * 9; i += 256) {     // 324 chunks of 8
            int r = i / 9, s = i - 9 * r;
            const float2* src = (const float2*)(img + (size_t)(tileY - 2 + r) * WW
                                                + (tileX - 2 + 8 * s));
            float2 v0 = src[0], v1 = src[1], v2 = src[2], v3 = src[3];
            int4 d;
            d.x = pk2(v0.y, v0.x);
            d.y = pk2(v1.y, v1.x);
            d.z = pk2(v2.y, v2.x);
            d.w = pk2(v3.y, v3.x);
            *(int4*)&tileS[r * RS + 8 * s] = d;
        }
    } else {
        for (int i = tid; i < NROW * NEL; i += 256) {
            int r = i / NEL, e = i - NEL * r;
            int gy = min(max(tileY - 2 + r, 0), HH - 1);
            int gx = min(max(tileX - 2 + e, 0), WW - 1);
            tileS[r * RS + e] = bf16rne(img[(size_t)gy * WW + gx]);
        }
    }
    __syncthreads();

    const int* tb = (const int*)tileS;     // 40 ints per row
    float* outp = out + (size_t)bimg * HH * WW;

    // ---- rolling 3-fragment B window over 4 row-pairs (8 rows per wave) ----
    union U { int4 v; s16x8 s; };
    U B0, B1, B2;
    {
        const int ia0 = (8 * w + h) * 40 + n;
        B0.v.x = tb[ia0];       B0.v.y = tb[ia0 + 1];
        B0.v.z = tb[ia0 + 2];   B0.v.w = tb[ia0 + 3];
        B1.v.x = tb[ia0 + 80];  B1.v.y = tb[ia0 + 81];
        B1.v.z = tb[ia0 + 82];  B1.v.w = tb[ia0 + 83];
        B2.v.x = tb[ia0 + 160]; B2.v.y = tb[ia0 + 161];
        B2.v.z = tb[ia0 + 162]; B2.v.w = tb[ia0 + 163];
    }

#pragma unroll
    for (int pp = 0; pp < 4; ++pp) {
        const int Rl = 8 * w + 2 * pp;     // local pair base row (even)
        const int y  = tileY + Rl;

        f32x16 a0 = (f32x16)(0.f), a1 = (f32x16)(0.f);
        a0 = __builtin_amdgcn_mfma_f32_32x32x16_bf16(Aa0, B0.s, a0, 0, 0, 0);
        a1 = __builtin_amdgcn_mfma_f32_32x32x16_bf16(Aa1, B0.s, a1, 0, 0, 0);
        a0 = __builtin_amdgcn_mfma_f32_32x32x16_bf16(Ab0, B1.s, a0, 0, 0, 0);
        a1 = __builtin_amdgcn_mfma_f32_32x32x16_bf16(Ab1, B1.s, a1, 0, 0, 0);
        a0 = __builtin_amdgcn_mfma_f32_32x32x16_bf16(Ac0, B2.s, a0, 0, 0, 0);
        a1 = __builtin_amdgcn_mfma_f32_32x32x16_bf16(Ac1, B2.s, a1, 0, 0, 0);

        // roll the window early so the loads overlap the epilogue
        if (pp < 3) {
            B0 = B1; B1 = B2;
            const int ia = (Rl + 6 + h) * 40 + n;
            B2.v.x = tb[ia];     B2.v.y = tb[ia + 1];
            B2.v.z = tb[ia + 2]; B2.v.w = tb[ia + 3];
        }

        // ---- epilogue: even row y (conv at odd x), odd row y+1 (conv even x)
        float den0 = 0.f, num0 = 0.f, den1 = 0.f, num1 = 0.f;
#pragma unroll
        for (int j = 0; j < 4; ++j) {
            float e0 = __expf(a0[2 * j]);
            den0 += e0;
            num0 = fmaf(e0, a0[2 * j + 1], num0);
            float e1 = __expf(a1[2 * j]);
            den1 += e1;
            num1 = fmaf(e1, a1[2 * j + 1], num1);
        }
        int ndA  = pk2(num0, den0);
        int ndB  = pk2(num1, den1);
        int ndA2 = __shfl_xor(ndA, 32);
        int ndB2 = __shfl_xor(ndB, 32);
        const float numA = num0 + hi16(ndA2);
        const float denA = den0 + lo16(ndA2);
        const float numB = num1 + hi16(ndB2);
        const float denB = den1 + lo16(ndB2);
        const float interpA = numA * __builtin_amdgcn_rcpf(denA);
        const float interpB = numB * __builtin_amdgcn_rcpf(denB);

        if (h == 0) {
            const int x0 = tileX + 2 * n;                  // even
            const float greenA = bf2f(tileS[(Rl + 2) * RS + 2 * n + 2]);
            const float greenB = bf2f(tileS[(Rl + 3) * RS + 2 * n + 3]);
            float2 stA; stA.x = greenA;  stA.y = interpA;
            float2 stB; stB.x = interpB; stB.y = greenB;
            *(float2*)(outp + (size_t)y * WW + x0)       = stA;
            *(float2*)(outp + (size_t)(y + 1) * WW + x0) = stB;
        }
    }
}

extern "C" void kernel_launch(void* const* d_in, const int* in_sizes, int n_in,
                              void* d_out, int out_size, void* d_ws, size_t ws_size,
                              hipStream_t stream) {
    const float* mos = (const float*)d_in[0];
    const float* sf  = (const float*)d_in[1];
    const float* gf  = (const float*)d_in[2];
    float* out = (float*)d_out;
    short* ws  = (short*)d_ws;

    const int B = in_sizes[0] / (HH * WW);     // 16

    build_frags_kernel<<<1, 64, 0, stream>>>(sf, gf, ws);

    dim3 grid(WW / TW, HH / TH, B);            // (8, 16, 16) = 2048 blocks
    dim3 block(256);
    demosaick_kernel<<<grid, block, 0, stream>>>(mos, (const short*)ws, out);
}